// Round 1
// baseline (316.950 us; speedup 1.0000x reference)
//
#include <hip/hip_runtime.h>

#define S_SEQ 256
#define N_RES 512
#define CCH   32
#define MK    (N_RES * CCH)   // 16384 rows of A/B
#define KDIM  S_SEQ           // 256

typedef __attribute__((ext_vector_type(8))) short bf16x8;
typedef __attribute__((ext_vector_type(4))) float f32x4;

__device__ __forceinline__ unsigned short f2bf(float x) {
    unsigned int u = __float_as_uint(x);
    unsigned int r = (u + 0x7FFFu + ((u >> 16) & 1u)) >> 16;
    return (unsigned short)r;
}

#define GLOAD_LDS16(gp, lp) __builtin_amdgcn_global_load_lds( \
    (const __attribute__((address_space(1))) unsigned int*)(gp), \
    (__attribute__((address_space(3))) unsigned int*)(lp), 16, 0, 0)

// ---------------------------------------------------------------------------
// Kernel 1: LayerNorm + dual projection + mask, write A/B bf16 in [N*C, S]
// (K-major) layout. One block per residue n; thread t handles sequence s=t.
// ---------------------------------------------------------------------------
__global__ __launch_bounds__(256) void prep_ab(
    const float* __restrict__ m, const float* __restrict__ mask,
    const float* __restrict__ gam, const float* __restrict__ bet,
    const float* __restrict__ Wa, const float* __restrict__ ba,
    const float* __restrict__ Wb, const float* __restrict__ bb,
    unsigned short* __restrict__ Abig, unsigned short* __restrict__ Bbig)
{
    __shared__ float WaL[1024], WbL[1024];
    __shared__ float gL[32], btL[32], baL[32], bbL[32];
    __shared__ unsigned short At[32 * 256];
    __shared__ unsigned short Bt[32 * 256];

    const int n = blockIdx.x;
    const int t = threadIdx.x;

    for (int i = t; i < 1024; i += 256) { WaL[i] = Wa[i]; WbL[i] = Wb[i]; }
    if (t < 32) { gL[t] = gam[t]; btL[t] = bet[t]; baL[t] = ba[t]; bbL[t] = bb[t]; }
    __syncthreads();

    const int s = t;
    float mv[32];
    const float* mrow = m + ((size_t)s * N_RES + n) * CCH;
#pragma unroll
    for (int c4 = 0; c4 < 8; c4++) {
        f32x4 v = *(const f32x4*)(mrow + c4 * 4);
        mv[c4 * 4 + 0] = v.x; mv[c4 * 4 + 1] = v.y;
        mv[c4 * 4 + 2] = v.z; mv[c4 * 4 + 3] = v.w;
    }
    float mu = 0.f;
#pragma unroll
    for (int c = 0; c < 32; c++) mu += mv[c];
    mu *= (1.f / 32.f);
    float var = 0.f;
#pragma unroll
    for (int c = 0; c < 32; c++) { float d = mv[c] - mu; var += d * d; }
    var *= (1.f / 32.f);
    float rs = rsqrtf(var + 1e-5f);
    float mh[32];
#pragma unroll
    for (int c = 0; c < 32; c++) mh[c] = (mv[c] - mu) * rs * gL[c] + btL[c];

    const float msk = mask[(size_t)s * N_RES + n];

    f32x4 av[8], bv[8];
#pragma unroll
    for (int cg = 0; cg < 8; cg++) { av[cg] = (f32x4)0.f; bv[cg] = (f32x4)0.f; }
#pragma unroll
    for (int k = 0; k < 32; k++) {
        float x = mh[k];
#pragma unroll
        for (int cg = 0; cg < 8; cg++) {
            f32x4 wa4 = *(const f32x4*)&WaL[k * 32 + cg * 4];
            f32x4 wb4 = *(const f32x4*)&WbL[k * 32 + cg * 4];
            av[cg] += x * wa4;
            bv[cg] += x * wb4;
        }
    }
#pragma unroll
    for (int cg = 0; cg < 8; cg++) {
#pragma unroll
        for (int u = 0; u < 4; u++) {
            int c = cg * 4 + u;
            float a = (av[cg][u] + baL[c]) * msk;
            float b = (bv[cg][u] + bbL[c]) * msk;
            At[c * 256 + s] = f2bf(a);
            Bt[c * 256 + s] = f2bf(b);
        }
    }
    __syncthreads();

    // coalesced flush: thread t writes 32 consecutive elems (64B)
    {
        const int base = t * 32;                 // elem index into [32][256]
        unsigned short* ga = Abig + (size_t)n * 8192 + base;
        unsigned short* gb = Bbig + (size_t)n * 8192 + base;
#pragma unroll
        for (int u = 0; u < 4; u++) {
            *(uint4*)(ga + u * 8) = *(const uint4*)(At + base + u * 8);
            *(uint4*)(gb + u * 8) = *(const uint4*)(Bt + base + u * 8);
        }
    }
}

// ---------------------------------------------------------------------------
// Kernel 2: Wt[k][ce] = bf16(Wout[ce][k])   (32 x 1024)
// ---------------------------------------------------------------------------
__global__ __launch_bounds__(256) void kwt(const float* __restrict__ Wout,
                                           unsigned short* __restrict__ Wt)
{
    int idx = blockIdx.x * 256 + threadIdx.x;   // 8192 threads, 4 elems each
    int k   = idx >> 8;
    int ce0 = (idx & 255) * 4;
#pragma unroll
    for (int u = 0; u < 4; u++)
        Wt[k * 1024 + ce0 + u] = f2bf(Wout[(size_t)(ce0 + u) * 32 + k]);
}

// ---------------------------------------------------------------------------
// Kernel 3: inv_norm[i][j] = 1 / (sum_s mask[s,i]*mask[s,j] + 1e-3)
// grid 8x8 blocks of 64x64 tile
// ---------------------------------------------------------------------------
__global__ __launch_bounds__(256) void knorm(const float* __restrict__ mask,
                                             float* __restrict__ inv_norm)
{
    __shared__ float Mi[64][65];
    __shared__ float Mj[64][65];
    const int bi = blockIdx.x >> 3, bj = blockIdx.x & 7;
    const int t = threadIdx.x;
    const int ty = t >> 4, tx = t & 15;

    float acc[4][4];
#pragma unroll
    for (int a = 0; a < 4; a++)
#pragma unroll
        for (int b = 0; b < 4; b++) acc[a][b] = 0.f;

    for (int sc = 0; sc < 4; sc++) {
        for (int e = t; e < 4096; e += 256) {
            int sr = e >> 6, col = e & 63;
            Mi[sr][col] = mask[(size_t)(sc * 64 + sr) * N_RES + bi * 64 + col];
            Mj[sr][col] = mask[(size_t)(sc * 64 + sr) * N_RES + bj * 64 + col];
        }
        __syncthreads();
        for (int sp = 0; sp < 64; sp++) {
#pragma unroll
            for (int a = 0; a < 4; a++)
#pragma unroll
                for (int b = 0; b < 4; b++)
                    acc[a][b] += Mi[sp][ty * 4 + a] * Mj[sp][tx * 4 + b];
        }
        __syncthreads();
    }
#pragma unroll
    for (int a = 0; a < 4; a++)
#pragma unroll
        for (int b = 0; b < 4; b++) {
            int i = bi * 64 + ty * 4 + a;
            int j = bj * 64 + tx * 4 + b;
            inv_norm[(size_t)i * N_RES + j] = 1.f / (acc[a][b] + 1e-3f);
        }
}

// ---------------------------------------------------------------------------
// Kernel 4: main fused GEMM.  G = A·B^T (M=N=16384, K=256, bf16, fp32 acc),
// tile 128x128 (4x4 residue pairs), epilogue: pair blocks -> LDS bf16,
// second MFMA GEMM vs Wt (K=1024 split over 4 waves) + reduce + bias + norm.
// ---------------------------------------------------------------------------
__global__ __launch_bounds__(256) void kmain(
    const unsigned short* __restrict__ A, const unsigned short* __restrict__ B,
    const unsigned short* __restrict__ Wt, const float* __restrict__ inv_norm,
    const float* __restrict__ bout, float* __restrict__ out)
{
    __shared__ __align__(16) char smraw[41216];
    unsigned short* As  = (unsigned short*)smraw;          // [128][32] bf16
    unsigned short* Bs  = As + 128 * 32;                   // [128][32] bf16
    unsigned short* G   = (unsigned short*)smraw;          // [16][1032] bf16
    float*          red = (float*)(smraw + 33024);         // [4][16][32] f32

    const int bid = blockIdx.x;
    const int swz = (bid & 7) * 2048 + (bid >> 3);         // XCD swizzle (16384 % 8 == 0)
    const int ti = swz >> 7, tj = swz & 127;

    const int t = threadIdx.x;
    const int lane = t & 63, wid = t >> 6;
    const int wr = wid >> 1, wc = wid & 1;                 // wave tile 64x64

    f32x4 acc[4][4];
#pragma unroll
    for (int a = 0; a < 4; a++)
#pragma unroll
        for (int b = 0; b < 4; b++) acc[a][b] = (f32x4)0.f;

    const size_t arow0 = (size_t)ti * 128;
    const size_t brow0 = (size_t)tj * 128;
    const int c0 = t, c1 = t + 256;                        // staging chunks
    const int r0 = c0 >> 2, k8_0 = (c0 & 3) * 8;
    const int r1 = c1 >> 2, k8_1 = (c1 & 3) * 8;

    const int rl = lane & 15;
    const int kh = (lane >> 4) * 8;

    for (int kt = 0; kt < 8; kt++) {
        const int k0 = kt * 32;
        GLOAD_LDS16(A + (arow0 + r0) * 256 + k0 + k8_0, As + c0 * 8);
        GLOAD_LDS16(A + (arow0 + r1) * 256 + k0 + k8_1, As + c1 * 8);
        GLOAD_LDS16(B + (brow0 + r0) * 256 + k0 + k8_0, Bs + c0 * 8);
        GLOAD_LDS16(B + (brow0 + r1) * 256 + k0 + k8_1, Bs + c1 * 8);
        __syncthreads();

        bf16x8 af[4], bf[4];
#pragma unroll
        for (int am = 0; am < 4; am++)
            af[am] = *(const bf16x8*)&As[(wr * 64 + am * 16 + rl) * 32 + kh];
#pragma unroll
        for (int bn = 0; bn < 4; bn++)
            bf[bn] = *(const bf16x8*)&Bs[(wc * 64 + bn * 16 + rl) * 32 + kh];
#pragma unroll
        for (int am = 0; am < 4; am++)
#pragma unroll
            for (int bn = 0; bn < 4; bn++)
                acc[am][bn] = __builtin_amdgcn_mfma_f32_16x16x32_bf16(
                    af[am], bf[bn], acc[am][bn], 0, 0, 0);
        __syncthreads();
    }

    // ---- epilogue: dump G pair-blocks to LDS as bf16 rows [pair][1024] ----
#pragma unroll
    for (int am = 0; am < 4; am++) {
#pragma unroll
        for (int bn = 0; bn < 4; bn++) {
#pragma unroll
            for (int r = 0; r < 4; r++) {
                int gm = wr * 64 + am * 16 + (lane >> 4) * 4 + r;
                int gn = wc * 64 + bn * 16 + (lane & 15);
                int p = (gm >> 5) * 4 + (gn >> 5);
                G[p * 1032 + (gm & 31) * 32 + (gn & 31)] = f2bf(acc[am][bn][r]);
            }
        }
    }
    __syncthreads();

    // ---- second GEMM: OUT[16 pairs x 32] = G[16x1024] @ Wt[32x1024]^T ----
    f32x4 acc_e[2];
    acc_e[0] = (f32x4)0.f; acc_e[1] = (f32x4)0.f;
#pragma unroll
    for (int kt2 = 0; kt2 < 8; kt2++) {
        const int k0 = wid * 256 + kt2 * 32;
        bf16x8 ga  = *(const bf16x8*)&G[rl * 1032 + k0 + kh];
        bf16x8 wb0 = *(const bf16x8*)&Wt[(size_t)rl * 1024 + k0 + kh];
        bf16x8 wb1 = *(const bf16x8*)&Wt[(size_t)(16 + rl) * 1024 + k0 + kh];
        acc_e[0] = __builtin_amdgcn_mfma_f32_16x16x32_bf16(ga, wb0, acc_e[0], 0, 0, 0);
        acc_e[1] = __builtin_amdgcn_mfma_f32_16x16x32_bf16(ga, wb1, acc_e[1], 0, 0, 0);
    }
#pragma unroll
    for (int nt = 0; nt < 2; nt++)
#pragma unroll
        for (int r = 0; r < 4; r++) {
            int p = (lane >> 4) * 4 + r;
            int k = nt * 16 + (lane & 15);
            red[wid * 512 + p * 32 + k] = acc_e[nt][r];
        }
    __syncthreads();

    // ---- reduce 4 waves + bias + mask-norm + store ----
    for (int idx = t; idx < 512; idx += 256) {
        int p = idx >> 5, k = idx & 31;
        float v = red[p * 32 + k] + red[512 + p * 32 + k] +
                  red[1024 + p * 32 + k] + red[1536 + p * 32 + k];
        int i = ti * 4 + (p >> 2);
        int j = tj * 4 + (p & 3);
        v = (v + bout[k]) * inv_norm[(size_t)i * N_RES + j];
        out[((size_t)i * N_RES + j) * CCH + k] = v;
    }
}

// ---------------------------------------------------------------------------
extern "C" void kernel_launch(void* const* d_in, const int* in_sizes, int n_in,
                              void* d_out, int out_size, void* d_ws, size_t ws_size,
                              hipStream_t stream)
{
    const float* m    = (const float*)d_in[0];
    const float* mask = (const float*)d_in[1];
    const float* gam  = (const float*)d_in[2];
    const float* bet  = (const float*)d_in[3];
    const float* Wa   = (const float*)d_in[4];
    const float* ba   = (const float*)d_in[5];
    const float* Wb   = (const float*)d_in[6];
    const float* bb   = (const float*)d_in[7];
    const float* Wout = (const float*)d_in[8];
    const float* bout = (const float*)d_in[9];
    float* out = (float*)d_out;

    unsigned short* Abig = (unsigned short*)d_ws;                  // 16384*256 bf16
    unsigned short* Bbig = Abig + (size_t)MK * KDIM;               // 16384*256 bf16
    unsigned short* Wt   = Bbig + (size_t)MK * KDIM;               // 32*1024 bf16
    float* inv_norm      = (float*)(Wt + 32 * 1024);               // 512*512 f32

    prep_ab<<<dim3(N_RES), dim3(256), 0, stream>>>(m, mask, gam, bet, Wa, ba, Wb, bb, Abig, Bbig);
    kwt<<<dim3(32), dim3(256), 0, stream>>>(Wout, Wt);
    knorm<<<dim3(64), dim3(256), 0, stream>>>(mask, inv_norm);
    kmain<<<dim3(16384), dim3(256), 0, stream>>>(Abig, Bbig, Wt, inv_norm, bout, out);
}

// Round 2
// 294.614 us; speedup vs baseline: 1.0758x; 1.0758x over previous
//
#include <hip/hip_runtime.h>

#define S_SEQ 256
#define N_RES 512
#define CCH   32

typedef __attribute__((ext_vector_type(8))) short bf16x8;
typedef __attribute__((ext_vector_type(4))) float f32x4;
typedef __attribute__((ext_vector_type(2))) unsigned int u32x2;

__device__ __forceinline__ unsigned short f2bf(float x) {
    unsigned int u = __float_as_uint(x);
    return (unsigned short)((u + 0x7FFFu + ((u >> 16) & 1u)) >> 16);
}

#define GLOAD_LDS16(gp, lp) __builtin_amdgcn_global_load_lds( \
    (const __attribute__((address_space(1))) unsigned int*)(gp), \
    (__attribute__((address_space(3))) unsigned int*)(lp), 16, 0, 0)

// ---------------------------------------------------------------------------
// Kernel 1: LayerNorm + dual projection + mask. Output layout is the exact
// byte image kmain2's global_load_lds staging expects:
//   per 256-row tile ti, per kt (64 seqs): row-major [256][64] bf16 with
//   16B-slot XOR swizzle: byte = ti*131072 + kt*32768 + row*128
//                              + ((k/8 ^ (row&7))*16 + (k%8)*2
// ---------------------------------------------------------------------------
__global__ __launch_bounds__(256) void prep_ab(
    const float* __restrict__ m, const float* __restrict__ mask,
    const float* __restrict__ gam, const float* __restrict__ bet,
    const float* __restrict__ Wa, const float* __restrict__ ba,
    const float* __restrict__ Wb, const float* __restrict__ bb,
    char* __restrict__ Ag, char* __restrict__ Bg)
{
    __shared__ float WaL[1024], WbL[1024];
    __shared__ float gL[32], btL[32], baL[32], bbL[32];
    __shared__ unsigned short At[32 * 256];
    __shared__ unsigned short Bt[32 * 256];

    const int n = blockIdx.x;
    const int t = threadIdx.x;

    for (int i = t; i < 1024; i += 256) { WaL[i] = Wa[i]; WbL[i] = Wb[i]; }
    if (t < 32) { gL[t] = gam[t]; btL[t] = bet[t]; baL[t] = ba[t]; bbL[t] = bb[t]; }
    __syncthreads();

    const int s = t;
    float mv[32];
    const float* mrow = m + ((size_t)s * N_RES + n) * CCH;
#pragma unroll
    for (int c4 = 0; c4 < 8; c4++) {
        f32x4 v = *(const f32x4*)(mrow + c4 * 4);
        mv[c4 * 4 + 0] = v.x; mv[c4 * 4 + 1] = v.y;
        mv[c4 * 4 + 2] = v.z; mv[c4 * 4 + 3] = v.w;
    }
    float mu = 0.f;
#pragma unroll
    for (int c = 0; c < 32; c++) mu += mv[c];
    mu *= (1.f / 32.f);
    float var = 0.f;
#pragma unroll
    for (int c = 0; c < 32; c++) { float d = mv[c] - mu; var += d * d; }
    var *= (1.f / 32.f);
    float rs = rsqrtf(var + 1e-5f);
    float mh[32];
#pragma unroll
    for (int c = 0; c < 32; c++) mh[c] = (mv[c] - mu) * rs * gL[c] + btL[c];

    const float msk = mask[(size_t)s * N_RES + n];

    f32x4 av[8], bv[8];
#pragma unroll
    for (int cg = 0; cg < 8; cg++) { av[cg] = (f32x4)0.f; bv[cg] = (f32x4)0.f; }
#pragma unroll
    for (int k = 0; k < 32; k++) {
        float x = mh[k];
#pragma unroll
        for (int cg = 0; cg < 8; cg++) {
            f32x4 wa4 = *(const f32x4*)&WaL[k * 32 + cg * 4];
            f32x4 wb4 = *(const f32x4*)&WbL[k * 32 + cg * 4];
            av[cg] += x * wa4;
            bv[cg] += x * wb4;
        }
    }
#pragma unroll
    for (int cg = 0; cg < 8; cg++) {
#pragma unroll
        for (int u = 0; u < 4; u++) {
            int c = cg * 4 + u;
            At[c * 256 + s] = f2bf((av[cg][u] + baL[c]) * msk);
            Bt[c * 256 + s] = f2bf((bv[cg][u] + bbL[c]) * msk);
        }
    }
    __syncthreads();

    // flush in kmain2's staged-LDS image layout (16B chunks, swizzled)
    const size_t tbase = (size_t)(n >> 3) * 131072;
#pragma unroll
    for (int u = 0; u < 4; u++) {
        int cid = t * 4 + u;             // 1024 chunks: c-row (32) x 8-seq group (32)
        int c = cid >> 5, g = cid & 31;
        int row = ((n & 7) << 5) + c;    // row within 256-row tile
        int slot = (g & 7) ^ (c & 7);    // (row&7) == (c&7)
        size_t off = tbase + (size_t)(g >> 3) * 32768 + (size_t)row * 128 + slot * 16;
        *(uint4*)(Ag + off) = *(const uint4*)(At + c * 256 + g * 8);
        *(uint4*)(Bg + off) = *(const uint4*)(Bt + c * 256 + g * 8);
    }
}

// ---------------------------------------------------------------------------
// Kernel 2: Wt2[ch][e*32 + c] = bf16(Wout[(c*32+e)][ch])    (32 x 1024)
// k-order e*32+c matches the transposed-within-pair G layout.
// ---------------------------------------------------------------------------
__global__ __launch_bounds__(256) void kwt(const float* __restrict__ Wout,
                                           unsigned short* __restrict__ Wt2)
{
    int idx = blockIdx.x * 256 + threadIdx.x;   // 32768
    int ch = idx >> 10, e = (idx >> 5) & 31, c = idx & 31;
    Wt2[idx] = f2bf(Wout[(size_t)(c * 32 + e) * 32 + ch]);
}

// ---------------------------------------------------------------------------
// Kernel 3: inv_norm[i][j] = 1 / (sum_s mask[s,i]*mask[s,j] + 1e-3)
// ---------------------------------------------------------------------------
__global__ __launch_bounds__(256) void knorm(const float* __restrict__ mask,
                                             float* __restrict__ inv_norm)
{
    __shared__ float Mi[64][65];
    __shared__ float Mj[64][65];
    const int bi = blockIdx.x >> 3, bj = blockIdx.x & 7;
    const int t = threadIdx.x;
    const int ty = t >> 4, tx = t & 15;

    float acc[4][4];
#pragma unroll
    for (int a = 0; a < 4; a++)
#pragma unroll
        for (int b = 0; b < 4; b++) acc[a][b] = 0.f;

    for (int sc = 0; sc < 4; sc++) {
        for (int e = t; e < 4096; e += 256) {
            int sr = e >> 6, col = e & 63;
            Mi[sr][col] = mask[(size_t)(sc * 64 + sr) * N_RES + bi * 64 + col];
            Mj[sr][col] = mask[(size_t)(sc * 64 + sr) * N_RES + bj * 64 + col];
        }
        __syncthreads();
        for (int sp = 0; sp < 64; sp++) {
#pragma unroll
            for (int a = 0; a < 4; a++)
#pragma unroll
                for (int b = 0; b < 4; b++)
                    acc[a][b] += Mi[sp][ty * 4 + a] * Mj[sp][tx * 4 + b];
        }
        __syncthreads();
    }
#pragma unroll
    for (int a = 0; a < 4; a++)
#pragma unroll
        for (int b = 0; b < 4; b++) {
            int i = bi * 64 + ty * 4 + a;
            int j = bj * 64 + tx * 4 + b;
            inv_norm[(size_t)i * N_RES + j] = 1.f / (acc[a][b] + 1e-3f);
        }
}

// ---------------------------------------------------------------------------
// Kernel 4: 256x256 tile, BK=64, 8 waves (2Mx4N), dbuf LDS + counted vmcnt.
// Epilogue: acc -> G LDS (bf16, pair-major, slot-XOR) -> MFMA @ Wt2 (K split
// over 2 wave-groups) -> LDS reduce -> bias + mask-norm -> store.
// ---------------------------------------------------------------------------
__global__ __launch_bounds__(512, 2) void kmain2(
    const char* __restrict__ Ag, const char* __restrict__ Bg,
    const unsigned short* __restrict__ Wt2, const float* __restrict__ inv_norm,
    const float* __restrict__ bout, float* __restrict__ out)
{
    __shared__ __align__(16) char sm[147968];   // [0,131072) staging dbuf; G overlays; red at 131584

    // XCD-aware 2D swizzle: each XCD gets an 8-ti stripe; within it, tj in
    // chunks of 16 so a 2MB B-chunk + 1MB A-stripe stay L2-resident.
    const int bid = blockIdx.x;
    const int xcd = bid & 7;
    const int xidx = bid >> 3;                 // 0..511
    const int chunk = xidx >> 7;               // 0..3
    const int TI = xcd * 8 + ((xidx >> 4) & 7);
    const int TJ = chunk * 16 + (xidx & 15);

    const int t = threadIdx.x;
    const int lane = t & 63, wid = t >> 6;
    const int wr = wid >> 2, wc = wid & 3;     // wave tile 128x64
    const int rl = lane & 15, h = lane >> 4;

    const char* pa = Ag + (size_t)TI * 131072;
    const char* pb = Bg + (size_t)TJ * 131072;

#define STAGE(kt, buf) do { \
    _Pragma("unroll") \
    for (int q = 0; q < 4; q++) { \
        GLOAD_LDS16(pa + (kt) * 32768 + q * 8192 + t * 16, sm + (buf) * 65536 + q * 8192 + t * 16); \
        GLOAD_LDS16(pb + (kt) * 32768 + q * 8192 + t * 16, sm + (buf) * 65536 + 32768 + q * 8192 + t * 16); \
    } } while (0)

    f32x4 acc[8][4];
#pragma unroll
    for (int a = 0; a < 8; a++)
#pragma unroll
        for (int b = 0; b < 4; b++) acc[a][b] = (f32x4)0.f;

#define COMPUTE(buf) do { \
    const char* As_ = sm + (buf) * 65536; \
    const char* Bs_ = As_ + 32768; \
    _Pragma("unroll") \
    for (int ks = 0; ks < 2; ks++) { \
        bf16x8 bfr[4]; \
        _Pragma("unroll") \
        for (int bn = 0; bn < 4; bn++) { \
            int brow = wc * 64 + bn * 16 + rl; \
            int bslot = (ks * 4 + h) ^ (brow & 7); \
            bfr[bn] = *(const bf16x8*)(Bs_ + brow * 128 + bslot * 16); \
        } \
        _Pragma("unroll") \
        for (int am = 0; am < 8; am++) { \
            int arow = wr * 128 + am * 16 + rl; \
            int aslot = (ks * 4 + h) ^ (arow & 7); \
            bf16x8 afr = *(const bf16x8*)(As_ + arow * 128 + aslot * 16); \
            _Pragma("unroll") \
            for (int bn = 0; bn < 4; bn++) \
                acc[am][bn] = __builtin_amdgcn_mfma_f32_16x16x32_bf16(afr, bfr[bn], acc[am][bn], 0, 0, 0); \
        } \
    } } while (0)

#define BAR()  __builtin_amdgcn_s_barrier(); asm volatile("" ::: "memory")
#define WLGKM0() asm volatile("s_waitcnt lgkmcnt(0)" ::: "memory")

    // prologue: stage kt0+kt1, wait kt0
    STAGE(0, 0);
    STAGE(1, 1);
    asm volatile("s_waitcnt vmcnt(8)" ::: "memory");
    BAR();

    // kt0
    __builtin_amdgcn_s_setprio(1); COMPUTE(0); __builtin_amdgcn_s_setprio(0);
    WLGKM0(); BAR();
    STAGE(2, 0);
    asm volatile("s_waitcnt vmcnt(8)" ::: "memory");
    BAR();
    // kt1
    __builtin_amdgcn_s_setprio(1); COMPUTE(1); __builtin_amdgcn_s_setprio(0);
    WLGKM0(); BAR();
    STAGE(3, 1);
    asm volatile("s_waitcnt vmcnt(8)" ::: "memory");
    BAR();
    // kt2
    __builtin_amdgcn_s_setprio(1); COMPUTE(0); __builtin_amdgcn_s_setprio(0);
    WLGKM0(); BAR();
    asm volatile("s_waitcnt vmcnt(0)" ::: "memory");
    BAR();
    // kt3
    __builtin_amdgcn_s_setprio(1); COMPUTE(1); __builtin_amdgcn_s_setprio(0);
    WLGKM0(); BAR();

    // ---- dump acc -> G: pair p = (gm/32)*8 + gn/32; within pair k' = e*32+c,
    // byte = p*2056 + e*64 + ((c/4 ^ (e&7))*8 + (c%4)*2; lane packs r=0..3 -> b64
#pragma unroll
    for (int am = 0; am < 8; am++) {
        const int pi = wr * 4 + (am >> 1);
        const int cslot = ((am & 1) << 2) + h;       // c/4
#pragma unroll
        for (int bn = 0; bn < 4; bn++) {
            const int pj = wc * 2 + (bn >> 1);
            const int e = ((bn & 1) << 4) + rl;
            const int p = pi * 8 + pj;
            unsigned int lo = (unsigned int)f2bf(acc[am][bn][0]) | ((unsigned int)f2bf(acc[am][bn][1]) << 16);
            unsigned int hi = (unsigned int)f2bf(acc[am][bn][2]) | ((unsigned int)f2bf(acc[am][bn][3]) << 16);
            u32x2 wv; wv[0] = lo; wv[1] = hi;
            *(u32x2*)(sm + p * 2056 + e * 64 + ((cslot ^ (e & 7)) << 3)) = wv;
        }
    }
    WLGKM0(); BAR();

    // ---- second GEMM: OUT[64 pairs][32] = G[64][1024] @ Wt2[32][1024]^T,
    // K split over wave-groups (hf), 16 pairs per wave.
    const int pquad = wid & 3, hf = wid >> 2;
    f32x4 ae[2];
    ae[0] = (f32x4)0.f; ae[1] = (f32x4)0.f;
    const char* grow = sm + (pquad * 16 + rl) * 2056;
#pragma unroll
    for (int es = 0; es < 16; es++) {
        const int e = hf * 16 + es;
        const int s0 = (2 * h) ^ (e & 7), s1 = (2 * h + 1) ^ (e & 7);
        union { unsigned long long q[2]; bf16x8 v; } uu;
        uu.q[0] = *(const unsigned long long*)(grow + e * 64 + s0 * 8);
        uu.q[1] = *(const unsigned long long*)(grow + e * 64 + s1 * 8);
#pragma unroll
        for (int nt = 0; nt < 2; nt++) {
            bf16x8 wb = *(const bf16x8*)(Wt2 + (size_t)(nt * 16 + rl) * 1024 + e * 32 + h * 8);
            ae[nt] = __builtin_amdgcn_mfma_f32_16x16x32_bf16(uu.v, wb, ae[nt], 0, 0, 0);
        }
    }
    float* red = (float*)(sm + 131584);     // [2][64][32] f32
#pragma unroll
    for (int nt = 0; nt < 2; nt++)
#pragma unroll
        for (int r = 0; r < 4; r++)
            red[hf * 2048 + (pquad * 16 + h * 4 + r) * 32 + nt * 16 + rl] = ae[nt][r];
    WLGKM0(); BAR();

    // ---- reduce halves + bias + mask-norm + coalesced store ----
    {
        const int p = t >> 3, ch4 = (t & 7) << 2;
        f32x4 v0 = *(const f32x4*)(red + p * 32 + ch4);
        f32x4 v1 = *(const f32x4*)(red + 2048 + p * 32 + ch4);
        f32x4 bo = *(const f32x4*)(bout + ch4);
        const int i = TI * 8 + (p >> 3), j = TJ * 8 + (p & 7);
        const float inv = inv_norm[(size_t)i * N_RES + j];
        f32x4 r = (v0 + v1 + bo) * inv;
        *(f32x4*)(out + ((size_t)i * N_RES + j) * CCH + ch4) = r;
    }
#undef STAGE
#undef COMPUTE
#undef BAR
#undef WLGKM0
}

// ---------------------------------------------------------------------------
extern "C" void kernel_launch(void* const* d_in, const int* in_sizes, int n_in,
                              void* d_out, int out_size, void* d_ws, size_t ws_size,
                              hipStream_t stream)
{
    const float* m    = (const float*)d_in[0];
    const float* mask = (const float*)d_in[1];
    const float* gam  = (const float*)d_in[2];
    const float* bet  = (const float*)d_in[3];
    const float* Wa   = (const float*)d_in[4];
    const float* ba   = (const float*)d_in[5];
    const float* Wb   = (const float*)d_in[6];
    const float* bb   = (const float*)d_in[7];
    const float* Wout = (const float*)d_in[8];
    const float* bout = (const float*)d_in[9];
    float* out = (float*)d_out;

    char* ws = (char*)d_ws;
    char* Ag = ws;                                      //  8,388,608 B
    char* Bg = ws + 8388608;                            //  8,388,608 B
    unsigned short* Wt2 = (unsigned short*)(ws + 16777216);   // 65,536 B
    float* inv_norm = (float*)(ws + 16842752);          //  1,048,576 B

    prep_ab<<<dim3(N_RES), dim3(256), 0, stream>>>(m, mask, gam, bet, Wa, ba, Wb, bb, Ag, Bg);
    kwt<<<dim3(128), dim3(256), 0, stream>>>(Wout, Wt2);
    knorm<<<dim3(64), dim3(256), 0, stream>>>(mask, inv_norm);
    kmain2<<<dim3(4096), dim3(512), 0, stream>>>(Ag, Bg, Wt2, inv_norm, bout, out);
}

// Round 3
// 254.522 us; speedup vs baseline: 1.2453x; 1.1575x over previous
//
#include <hip/hip_runtime.h>

#define S_SEQ 256
#define N_RES 512
#define CCH   32

typedef __attribute__((ext_vector_type(8))) short bf16x8;
typedef __attribute__((ext_vector_type(4))) float f32x4;
typedef __attribute__((ext_vector_type(2))) unsigned int u32x2;

__device__ __forceinline__ unsigned short f2bf(float x) {
    unsigned int u = __float_as_uint(x);
    return (unsigned short)((u + 0x7FFFu + ((u >> 16) & 1u)) >> 16);
}

#define GLOAD_LDS16(gp, lp) __builtin_amdgcn_global_load_lds( \
    (const __attribute__((address_space(1))) unsigned int*)(gp), \
    (__attribute__((address_space(3))) unsigned int*)(lp), 16, 0, 0)

#define BAR()    do { __builtin_amdgcn_s_barrier(); asm volatile("" ::: "memory"); } while (0)
#define WLGKM0() asm volatile("s_waitcnt lgkmcnt(0)" ::: "memory")
#define WVM(n)   asm volatile("s_waitcnt vmcnt(" #n ")" ::: "memory")

// ---------------------------------------------------------------------------
// Kernel 1: LayerNorm + dual projection + mask. Writes A/B bf16 as the exact
// staged-LDS byte image kmain3 expects, per 256-row tile:
//   byte(kt,row,k) = kt*16384 + (row>>7)*8192 + (row&127)*64
//                  + (((k>>3) ^ (row&3))*16) + (k&7)*2      (kt = k-tile of 32)
// ---------------------------------------------------------------------------
__global__ __launch_bounds__(256) void prep_ab(
    const float* __restrict__ m, const float* __restrict__ mask,
    const float* __restrict__ gam, const float* __restrict__ bet,
    const float* __restrict__ Wa, const float* __restrict__ ba,
    const float* __restrict__ Wb, const float* __restrict__ bb,
    char* __restrict__ Ag, char* __restrict__ Bg)
{
    __shared__ float WaL[1024], WbL[1024];
    __shared__ float gL[32], btL[32], baL[32], bbL[32];
    __shared__ unsigned short At[32 * 256];
    __shared__ unsigned short Bt[32 * 256];

    const int n = blockIdx.x;
    const int t = threadIdx.x;

    for (int i = t; i < 1024; i += 256) { WaL[i] = Wa[i]; WbL[i] = Wb[i]; }
    if (t < 32) { gL[t] = gam[t]; btL[t] = bet[t]; baL[t] = ba[t]; bbL[t] = bb[t]; }
    __syncthreads();

    const int s = t;
    float mv[32];
    const float* mrow = m + ((size_t)s * N_RES + n) * CCH;
#pragma unroll
    for (int c4 = 0; c4 < 8; c4++) {
        f32x4 v = *(const f32x4*)(mrow + c4 * 4);
        mv[c4 * 4 + 0] = v.x; mv[c4 * 4 + 1] = v.y;
        mv[c4 * 4 + 2] = v.z; mv[c4 * 4 + 3] = v.w;
    }
    float mu = 0.f;
#pragma unroll
    for (int c = 0; c < 32; c++) mu += mv[c];
    mu *= (1.f / 32.f);
    float var = 0.f;
#pragma unroll
    for (int c = 0; c < 32; c++) { float d = mv[c] - mu; var += d * d; }
    var *= (1.f / 32.f);
    float rs = rsqrtf(var + 1e-5f);
    float mh[32];
#pragma unroll
    for (int c = 0; c < 32; c++) mh[c] = (mv[c] - mu) * rs * gL[c] + btL[c];

    const float msk = mask[(size_t)s * N_RES + n];

    f32x4 av[8], bv[8];
#pragma unroll
    for (int cg = 0; cg < 8; cg++) { av[cg] = (f32x4)0.f; bv[cg] = (f32x4)0.f; }
#pragma unroll
    for (int k = 0; k < 32; k++) {
        float x = mh[k];
#pragma unroll
        for (int cg = 0; cg < 8; cg++) {
            f32x4 wa4 = *(const f32x4*)&WaL[k * 32 + cg * 4];
            f32x4 wb4 = *(const f32x4*)&WbL[k * 32 + cg * 4];
            av[cg] += x * wa4;
            bv[cg] += x * wb4;
        }
    }
#pragma unroll
    for (int cg = 0; cg < 8; cg++) {
#pragma unroll
        for (int u = 0; u < 4; u++) {
            int c = cg * 4 + u;
            At[c * 256 + s] = f2bf((av[cg][u] + baL[c]) * msk);
            Bt[c * 256 + s] = f2bf((bv[cg][u] + bbL[c]) * msk);
        }
    }
    __syncthreads();

    // flush in kmain3's staged-LDS image (16B chunks)
    const size_t tbase = (size_t)(n >> 3) * 131072;
    const int halfo = ((n >> 2) & 1) * 8192;
    const int rbase = (n & 3) * 32;
#pragma unroll
    for (int u = 0; u < 4; u++) {
        int cid = t * 4 + u;             // 1024 chunks: c (32) x 8-seq group g (32)
        int c = cid >> 5, g = cid & 31;
        size_t off = tbase + (size_t)(g >> 2) * 16384 + halfo
                   + (size_t)(rbase + c) * 64 + (size_t)(((g & 3) ^ (c & 3)) << 4);
        *(uint4*)(Ag + off) = *(const uint4*)(At + c * 256 + g * 8);
        *(uint4*)(Bg + off) = *(const uint4*)(Bt + c * 256 + g * 8);
    }
}

// ---------------------------------------------------------------------------
// Kernel 2: Wt3[e][ch][c] = bf16(Wout[(c*32+e)][ch])   (32 x 32 x 32 bf16)
// ---------------------------------------------------------------------------
__global__ __launch_bounds__(256) void kwt(const float* __restrict__ Wout,
                                           unsigned short* __restrict__ Wt3)
{
    int idx = blockIdx.x * 256 + threadIdx.x;   // 32768
    int e = idx >> 10, ch = (idx >> 5) & 31, c = idx & 31;
    Wt3[idx] = f2bf(Wout[(size_t)(c * 32 + e) * 32 + ch]);
}

// ---------------------------------------------------------------------------
// Kernel 3: inv_norm[i][j] = 1 / (sum_s mask[s,i]*mask[s,j] + 1e-3)
// ---------------------------------------------------------------------------
__global__ __launch_bounds__(256) void knorm(const float* __restrict__ mask,
                                             float* __restrict__ inv_norm)
{
    __shared__ float Mi[64][65];
    __shared__ float Mj[64][65];
    const int bi = blockIdx.x >> 3, bj = blockIdx.x & 7;
    const int t = threadIdx.x;
    const int ty = t >> 4, tx = t & 15;

    float acc[4][4];
#pragma unroll
    for (int a = 0; a < 4; a++)
#pragma unroll
        for (int b = 0; b < 4; b++) acc[a][b] = 0.f;

    for (int sc = 0; sc < 4; sc++) {
        for (int e = t; e < 4096; e += 256) {
            int sr = e >> 6, col = e & 63;
            Mi[sr][col] = mask[(size_t)(sc * 64 + sr) * N_RES + bi * 64 + col];
            Mj[sr][col] = mask[(size_t)(sc * 64 + sr) * N_RES + bj * 64 + col];
        }
        __syncthreads();
        for (int sp = 0; sp < 64; sp++) {
#pragma unroll
            for (int a = 0; a < 4; a++)
#pragma unroll
                for (int b = 0; b < 4; b++)
                    acc[a][b] += Mi[sp][ty * 4 + a] * Mj[sp][tx * 4 + b];
        }
        __syncthreads();
    }
#pragma unroll
    for (int a = 0; a < 4; a++)
#pragma unroll
        for (int b = 0; b < 4; b++) {
            int i = bi * 64 + ty * 4 + a;
            int j = bj * 64 + tx * 4 + b;
            inv_norm[(size_t)i * N_RES + j] = 1.f / (acc[a][b] + 1e-3f);
        }
}

// ---------------------------------------------------------------------------
// Kernel 4: 256x256 tile, BK=32, 8 K-tiles, TRI-buffered LDS, 16-phase
// schedule (2 phases/KT, counted vmcnt(4) per KT, setprio on MFMA clusters).
// Epilogue: acc -> G LDS (stride 2064, 16B-XOR) -> per-wave MFMA vs Wt3
// (K split over 2 wave halves) -> sequential f32 reduce in out_sm -> store.
// ---------------------------------------------------------------------------
__global__ __launch_bounds__(512) void kmain3(
    const char* __restrict__ Ag, const char* __restrict__ Bg,
    const unsigned short* __restrict__ Wt3, const float* __restrict__ inv_norm,
    const float* __restrict__ bout, float* __restrict__ out)
{
    __shared__ __align__(16) char sm[140288];  // main: 3 x 32768; epi: G 132096 + outsm 8192

    const int bid = blockIdx.x;
    const int xcd = bid & 7;
    const int xidx = bid >> 3;
    const int chunk = xidx >> 7;
    const int TI = xcd * 8 + ((xidx >> 4) & 7);
    const int TJ = chunk * 16 + (xidx & 15);

    const int t = threadIdx.x;
    const int lane = t & 63, wid = t >> 6;
    const int wr = wid >> 2, wc = wid & 3;     // wave tile 128x64
    const int rl = lane & 15, h4 = lane >> 4;

    const char* pa = Ag + (size_t)TI * 131072;
    const char* pb = Bg + (size_t)TJ * 131072;

#define SH(kt, mx, half) GLOAD_LDS16( \
    ((mx) ? pb : pa) + (kt) * 16384 + (half) * 8192 + t * 16, \
    sm + ((kt) % 3) * 32768 + (mx) * 16384 + (half) * 8192 + t * 16)

    f32x4 acc[8][4];
#pragma unroll
    for (int a = 0; a < 8; a++)
#pragma unroll
        for (int b = 0; b < 4; b++) acc[a][b] = (f32x4)0.f;

    // prologue: stage KT0..KT2 (12 loads/thread), wait KT0
#pragma unroll
    for (int kt = 0; kt < 3; kt++) {
        SH(kt, 0, 0); SH(kt, 0, 1); SH(kt, 1, 0); SH(kt, 1, 1);
    }
    WVM(8);
    BAR();

#pragma unroll
    for (int kt = 0; kt < 8; kt++) {
        const int bs = (kt % 3) * 32768;
        bf16x8 af[8], bfr[2];
        // ---- phase A: read all A-frags + B cols 0..31, stage next A ----
#pragma unroll
        for (int am = 0; am < 8; am++) {
            const int row = wr * 128 + am * 16 + rl;
            af[am] = *(const bf16x8*)(sm + bs + ((row >> 7) * 8192)
                     + (row & 127) * 64 + ((h4 ^ (row & 3)) << 4));
        }
#pragma unroll
        for (int bb = 0; bb < 2; bb++) {
            const int row = wc * 64 + bb * 16 + rl;
            bfr[bb] = *(const bf16x8*)(sm + bs + 16384 + ((row >> 7) * 8192)
                      + (row & 127) * 64 + ((h4 ^ (row & 3)) << 4));
        }
        if (kt >= 1 && kt <= 5) { SH(kt + 2, 0, 0); SH(kt + 2, 0, 1); }
        BAR();
        WLGKM0();
        __builtin_amdgcn_s_setprio(1);
#pragma unroll
        for (int am = 0; am < 8; am++)
#pragma unroll
            for (int bb = 0; bb < 2; bb++)
                acc[am][bb] = __builtin_amdgcn_mfma_f32_16x16x32_bf16(
                    af[am], bfr[bb], acc[am][bb], 0, 0, 0);
        __builtin_amdgcn_s_setprio(0);
        BAR();
        // ---- phase B: read B cols 32..63, stage next B, gate next KT ----
#pragma unroll
        for (int bb = 0; bb < 2; bb++) {
            const int row = wc * 64 + (2 + bb) * 16 + rl;
            bfr[bb] = *(const bf16x8*)(sm + bs + 16384 + ((row >> 7) * 8192)
                      + (row & 127) * 64 + ((h4 ^ (row & 3)) << 4));
        }
        if (kt >= 1 && kt <= 5) { SH(kt + 2, 1, 0); SH(kt + 2, 1, 1); }
        BAR();
        WLGKM0();
        __builtin_amdgcn_s_setprio(1);
#pragma unroll
        for (int am = 0; am < 8; am++)
#pragma unroll
            for (int bb = 0; bb < 2; bb++)
                acc[am][2 + bb] = __builtin_amdgcn_mfma_f32_16x16x32_bf16(
                    af[am], bfr[bb], acc[am][2 + bb], 0, 0, 0);
        __builtin_amdgcn_s_setprio(0);
        if (kt <= 5) { WVM(4); } else if (kt == 6) { WVM(0); }
        BAR();
    }
#undef SH

    // ---- epilogue: dump acc -> G (pair-major, stride 2064, 16B XOR) ----
#pragma unroll
    for (int am = 0; am < 8; am++) {
#pragma unroll
        for (int bn = 0; bn < 4; bn++) {
            const int p = (wr * 4 + (am >> 1)) * 8 + wc * 2 + (bn >> 1);
            const int e = ((bn & 1) << 4) + rl;
            const int cs = ((am & 1) << 1) + (h4 >> 1);
            unsigned int lo = (unsigned int)f2bf(acc[am][bn][0]) | ((unsigned int)f2bf(acc[am][bn][1]) << 16);
            unsigned int hi = (unsigned int)f2bf(acc[am][bn][2]) | ((unsigned int)f2bf(acc[am][bn][3]) << 16);
            u32x2 wv; wv[0] = lo; wv[1] = hi;
            *(u32x2*)(sm + p * 2064 + e * 64 + ((cs ^ (e & 3)) << 4) + ((h4 & 1) << 3)) = wv;
        }
    }
    WLGKM0();
    BAR();

    // ---- second GEMM: OUT[64 pairs][32ch], pairs split 4 ways (pg),
    //      K=1024 split over 2 wave-halves (hf), full 16-row MFMA ----
    const int pg = wid & 3, hf = wid >> 2;
    f32x4 ae[2];
    ae[0] = (f32x4)0.f; ae[1] = (f32x4)0.f;
    const char* grow = sm + (pg * 16 + rl) * 2064;
#pragma unroll
    for (int ks = 0; ks < 16; ks++) {
        const int e = hf * 16 + ks;
        bf16x8 ga = *(const bf16x8*)(grow + e * 64 + ((h4 ^ (e & 3)) << 4));
#pragma unroll
        for (int nt = 0; nt < 2; nt++) {
            bf16x8 wb = *(const bf16x8*)(Wt3 + (size_t)e * 1024 + (nt * 16 + rl) * 32 + h4 * 8);
            ae[nt] = __builtin_amdgcn_mfma_f32_16x16x32_bf16(ga, wb, ae[nt], 0, 0, 0);
        }
    }
    float* outsm = (float*)(sm + 132096);
    if (hf == 0) {
#pragma unroll
        for (int nt = 0; nt < 2; nt++)
#pragma unroll
            for (int r = 0; r < 4; r++)
                outsm[(pg * 16 + h4 * 4 + r) * 32 + nt * 16 + rl] = ae[nt][r];
    }
    WLGKM0();
    BAR();
    if (hf == 1) {
#pragma unroll
        for (int nt = 0; nt < 2; nt++)
#pragma unroll
            for (int r = 0; r < 4; r++)
                outsm[(pg * 16 + h4 * 4 + r) * 32 + nt * 16 + rl] += ae[nt][r];
    }
    WLGKM0();
    BAR();

    // ---- bias + mask-norm + coalesced store ----
    {
        const int p = t >> 3, c4 = (t & 7) << 2;
        f32x4 v = *(const f32x4*)(outsm + p * 32 + c4);
        f32x4 bo = *(const f32x4*)(bout + c4);
        const int i = TI * 8 + (p >> 3), j = TJ * 8 + (p & 7);
        const float inv = inv_norm[(size_t)i * N_RES + j];
        f32x4 r = (v + bo) * inv;
        *(f32x4*)(out + ((size_t)(i * N_RES + j)) * CCH + c4) = r;
    }
}

// ---------------------------------------------------------------------------
extern "C" void kernel_launch(void* const* d_in, const int* in_sizes, int n_in,
                              void* d_out, int out_size, void* d_ws, size_t ws_size,
                              hipStream_t stream)
{
    const float* m    = (const float*)d_in[0];
    const float* mask = (const float*)d_in[1];
    const float* gam  = (const float*)d_in[2];
    const float* bet  = (const float*)d_in[3];
    const float* Wa   = (const float*)d_in[4];
    const float* ba   = (const float*)d_in[5];
    const float* Wb   = (const float*)d_in[6];
    const float* bb   = (const float*)d_in[7];
    const float* Wout = (const float*)d_in[8];
    const float* bout = (const float*)d_in[9];
    float* out = (float*)d_out;

    char* ws = (char*)d_ws;
    char* Ag = ws;                                            //  8,388,608 B
    char* Bg = ws + 8388608;                                  //  8,388,608 B
    unsigned short* Wt3 = (unsigned short*)(ws + 16777216);   //     65,536 B
    float* inv_norm = (float*)(ws + 16842752);                //  1,048,576 B

    prep_ab<<<dim3(N_RES), dim3(256), 0, stream>>>(m, mask, gam, bet, Wa, ba, Wb, bb, Ag, Bg);
    kwt<<<dim3(128), dim3(256), 0, stream>>>(Wout, Wt3);
    knorm<<<dim3(64), dim3(256), 0, stream>>>(mask, inv_norm);
    kmain3<<<dim3(4096), dim3(512), 0, stream>>>(Ag, Bg, Wt3, inv_norm, bout, out);
}

// Round 5
// 241.344 us; speedup vs baseline: 1.3133x; 1.0546x over previous
//
#include <hip/hip_runtime.h>

#define S_SEQ 256
#define N_RES 512
#define CCH   32

typedef __attribute__((ext_vector_type(8))) short bf16x8;
typedef __attribute__((ext_vector_type(4))) float f32x4;
typedef __attribute__((ext_vector_type(2))) unsigned int u32x2;

__device__ __forceinline__ unsigned short f2bf(float x) {
    unsigned int u = __float_as_uint(x);
    return (unsigned short)((u + 0x7FFFu + ((u >> 16) & 1u)) >> 16);
}

#define GLOAD_LDS16(gp, lp) __builtin_amdgcn_global_load_lds( \
    (const __attribute__((address_space(1))) unsigned int*)(gp), \
    (__attribute__((address_space(3))) unsigned int*)(lp), 16, 0, 0)

#define BAR()    do { __builtin_amdgcn_s_barrier(); asm volatile("" ::: "memory"); } while (0)
#define WLGKM0() asm volatile("s_waitcnt lgkmcnt(0)" ::: "memory")
#define WVM(n)   asm volatile("s_waitcnt vmcnt(" #n ")" ::: "memory")

// ---------------------------------------------------------------------------
// Kernel 1: LayerNorm + dual projection + mask. Writes A/B bf16 as the exact
// LDS byte image kmain5 stages. Per 256-row tile, per KT (32 seqs):
//   rows r and r+128 share a 128-B image row ir = r&127 (8 slots of 16 B):
//   byte = kt*16384 + ir*128 + ((((r>>7)<<2)|(k>>3)) ^ (ir&7))*16 + (k&7)*2
// Conflict-free: a wave's b128 frag read hits each 16B slot-column exactly
// 8 times (bank = slot*4 only, since ir*128/4 mod 32 == 0).
// ---------------------------------------------------------------------------
__global__ __launch_bounds__(256) void prep_ab(
    const float* __restrict__ m, const float* __restrict__ mask,
    const float* __restrict__ gam, const float* __restrict__ bet,
    const float* __restrict__ Wa, const float* __restrict__ ba,
    const float* __restrict__ Wb, const float* __restrict__ bb,
    char* __restrict__ Ag, char* __restrict__ Bg)
{
    __shared__ float WaL[1024], WbL[1024];
    __shared__ float gL[32], btL[32], baL[32], bbL[32];
    __shared__ unsigned short At[32 * 256];
    __shared__ unsigned short Bt[32 * 256];

    const int n = blockIdx.x;
    const int t = threadIdx.x;

    for (int i = t; i < 1024; i += 256) { WaL[i] = Wa[i]; WbL[i] = Wb[i]; }
    if (t < 32) { gL[t] = gam[t]; btL[t] = bet[t]; baL[t] = ba[t]; bbL[t] = bb[t]; }
    __syncthreads();

    const int s = t;
    float mv[32];
    const float* mrow = m + ((size_t)s * N_RES + n) * CCH;
#pragma unroll
    for (int c4 = 0; c4 < 8; c4++) {
        f32x4 v = *(const f32x4*)(mrow + c4 * 4);
        mv[c4 * 4 + 0] = v.x; mv[c4 * 4 + 1] = v.y;
        mv[c4 * 4 + 2] = v.z; mv[c4 * 4 + 3] = v.w;
    }
    float mu = 0.f;
#pragma unroll
    for (int c = 0; c < 32; c++) mu += mv[c];
    mu *= (1.f / 32.f);
    float var = 0.f;
#pragma unroll
    for (int c = 0; c < 32; c++) { float d = mv[c] - mu; var += d * d; }
    var *= (1.f / 32.f);
    float rs = rsqrtf(var + 1e-5f);
    float mh[32];
#pragma unroll
    for (int c = 0; c < 32; c++) mh[c] = (mv[c] - mu) * rs * gL[c] + btL[c];

    const float msk = mask[(size_t)s * N_RES + n];

    f32x4 av[8], bv[8];
#pragma unroll
    for (int cg = 0; cg < 8; cg++) { av[cg] = (f32x4)0.f; bv[cg] = (f32x4)0.f; }
#pragma unroll
    for (int k = 0; k < 32; k++) {
        float x = mh[k];
#pragma unroll
        for (int cg = 0; cg < 8; cg++) {
            f32x4 wa4 = *(const f32x4*)&WaL[k * 32 + cg * 4];
            f32x4 wb4 = *(const f32x4*)&WbL[k * 32 + cg * 4];
            av[cg] += x * wa4;
            bv[cg] += x * wb4;
        }
    }
#pragma unroll
    for (int cg = 0; cg < 8; cg++) {
#pragma unroll
        for (int u = 0; u < 4; u++) {
            int c = cg * 4 + u;
            At[c * 256 + s] = f2bf((av[cg][u] + baL[c]) * msk);
            Bt[c * 256 + s] = f2bf((bv[cg][u] + bbL[c]) * msk);
        }
    }
    __syncthreads();

    // flush in kmain5's dual-row 128B image (16B chunks)
    const size_t tbase = (size_t)(n >> 3) * 131072;
    const int half = (n >> 2) & 1;                 // r = (n&7)*32 + c ; half = r>>7
    const int irbase = (n & 3) * 32;               // ir = r&127
#pragma unroll
    for (int u = 0; u < 4; u++) {
        int cid = t * 4 + u;             // 1024 chunks: c (32) x 8-seq group g (32)
        int c = cid >> 5, g = cid & 31;
        int kt = g >> 2, q = g & 3;      // s = kt*32 + q*8 + j
        int slot = ((half << 2) | q) ^ (c & 7);    // ir&7 == c&7
        size_t off = tbase + (size_t)kt * 16384 + (size_t)(irbase + c) * 128 + (slot << 4);
        *(uint4*)(Ag + off) = *(const uint4*)(At + c * 256 + g * 8);
        *(uint4*)(Bg + off) = *(const uint4*)(Bt + c * 256 + g * 8);
    }
}

// ---------------------------------------------------------------------------
// Kernel 2: Wt3[e][ch][c] = bf16(Wout[(c*32+e)][ch])   (32 x 32 x 32 bf16)
// ---------------------------------------------------------------------------
__global__ __launch_bounds__(256) void kwt(const float* __restrict__ Wout,
                                           unsigned short* __restrict__ Wt3)
{
    int idx = blockIdx.x * 256 + threadIdx.x;   // 32768
    int e = idx >> 10, ch = (idx >> 5) & 31, c = idx & 31;
    Wt3[idx] = f2bf(Wout[(size_t)(c * 32 + e) * 32 + ch]);
}

// ---------------------------------------------------------------------------
// Kernel 3: inv_norm[i][j] = 1 / (sum_s mask[s,i]*mask[s,j] + 1e-3)
// ---------------------------------------------------------------------------
__global__ __launch_bounds__(256) void knorm(const float* __restrict__ mask,
                                             float* __restrict__ inv_norm)
{
    __shared__ float Mi[64][65];
    __shared__ float Mj[64][65];
    const int bi = blockIdx.x >> 3, bj = blockIdx.x & 7;
    const int t = threadIdx.x;
    const int ty = t >> 4, tx = t & 15;

    float acc[4][4];
#pragma unroll
    for (int a = 0; a < 4; a++)
#pragma unroll
        for (int b = 0; b < 4; b++) acc[a][b] = 0.f;

    for (int sc = 0; sc < 4; sc++) {
        for (int e = t; e < 4096; e += 256) {
            int sr = e >> 6, col = e & 63;
            Mi[sr][col] = mask[(size_t)(sc * 64 + sr) * N_RES + bi * 64 + col];
            Mj[sr][col] = mask[(size_t)(sc * 64 + sr) * N_RES + bj * 64 + col];
        }
        __syncthreads();
        for (int sp = 0; sp < 64; sp++) {
#pragma unroll
            for (int a = 0; a < 4; a++)
#pragma unroll
                for (int b = 0; b < 4; b++)
                    acc[a][b] += Mi[sp][ty * 4 + a] * Mj[sp][tx * 4 + b];
        }
        __syncthreads();
    }
#pragma unroll
    for (int a = 0; a < 4; a++)
#pragma unroll
        for (int b = 0; b < 4; b++) {
            int i = bi * 64 + ty * 4 + a;
            int j = bj * 64 + tx * 4 + b;
            inv_norm[(size_t)i * N_RES + j] = 1.f / (acc[a][b] + 1e-3f);
        }
}

// ---------------------------------------------------------------------------
// Kernel 5: 256x256 tile, BK=32, TRI-buffer (3x32KB), counted-vmcnt schedule:
// one barrier per KT; WVM(4) keeps next KT's loads in flight across it;
// SH(kt+2) issued right after the barrier. Conflict-free frag reads.
// Epilogue (r4-verified): 2 rounds x 2 slots of 16 pairs: G bf16 (stride
// 2064, 16B-XOR) -> full-M MFMA vs Wt3 (K split 4 ways) -> padded partials
// -> reduce + bias + mask-norm + store.
// ---------------------------------------------------------------------------
__global__ __launch_bounds__(512) void kmain5(
    const char* __restrict__ Ag, const char* __restrict__ Bg,
    const unsigned short* __restrict__ Wt3, const float* __restrict__ inv_norm,
    const float* __restrict__ bout, float* __restrict__ out)
{
    __shared__ __align__(16) char sm[98304];   // 3 x 32768 staging; epi overlays [0,66048)

    const int bid = blockIdx.x;
    const int xcd = bid & 7;
    const int xidx = bid >> 3;
    const int chunk = xidx >> 7;
    const int TI = xcd * 8 + ((xidx >> 4) & 7);
    const int TJ = chunk * 16 + (xidx & 15);

    const int t = threadIdx.x;
    const int lane = t & 63, wid = t >> 6;
    const int wr = wid >> 2, wc = wid & 3;     // wave tile 128x64
    const int rl = lane & 15, h4 = lane >> 4;

    const char* pa = Ag + (size_t)TI * 131072;
    const char* pb = Bg + (size_t)TJ * 131072;

#define SH(kt) do { \
    char* db_ = sm + (((kt) % 3) * 32768); \
    GLOAD_LDS16(pa + (kt) * 16384 + t * 16,        db_ + t * 16); \
    GLOAD_LDS16(pa + (kt) * 16384 + 8192 + t * 16, db_ + 8192 + t * 16); \
    GLOAD_LDS16(pb + (kt) * 16384 + t * 16,        db_ + 16384 + t * 16); \
    GLOAD_LDS16(pb + (kt) * 16384 + 8192 + t * 16, db_ + 24576 + t * 16); \
} while (0)

    // lane-constant parts of frag offsets
    const int aslot = ((wr << 2) | h4) ^ (rl & 7);
    const int bslot = (((wc >> 1) << 2) | h4) ^ (rl & 7);
    const int abase = rl * 128 + (aslot << 4);                              // + am*2048
    const int bbase = 16384 + ((wc & 1) * 64 + rl) * 128 + (bslot << 4);    // + bn*2048

    f32x4 acc[8][4];
#pragma unroll
    for (int a = 0; a < 8; a++)
#pragma unroll
        for (int b = 0; b < 4; b++) acc[a][b] = (f32x4)0.f;

    SH(0);
    SH(1);

#pragma unroll
    for (int kt = 0; kt < 8; kt++) {
        const char* buf = sm + ((kt % 3) * 32768);
        if (kt < 7) { WVM(4); } else { WVM(0); }
        WLGKM0();                       // retire prior-iter ds_reads pre-barrier
        BAR();
        if (kt < 6) SH(kt + 2);
        bf16x8 af[8], bfr[4];
#pragma unroll
        for (int am = 0; am < 8; am++)
            af[am] = *(const bf16x8*)(buf + abase + am * 2048);
#pragma unroll
        for (int bn = 0; bn < 4; bn++)
            bfr[bn] = *(const bf16x8*)(buf + bbase + bn * 2048);
        __builtin_amdgcn_s_setprio(1);
#pragma unroll
        for (int am = 0; am < 8; am++)
#pragma unroll
            for (int bn = 0; bn < 4; bn++)
                acc[am][bn] = __builtin_amdgcn_mfma_f32_16x16x32_bf16(
                    af[am], bfr[bn], acc[am][bn], 0, 0, 0);
        __builtin_amdgcn_s_setprio(0);
    }
#undef SH

    WLGKM0();
    BAR();

    // ================= epilogue: 2 rounds of (2 chunk-slots x 16 pairs) ====
    float* ps = (float*)sm;                       // [8][16][34] f32, overlays slot0
#pragma unroll
    for (int R = 0; R < 2; R++) {
        // ---- G writes: this round uses am = R*4 + a ----
#pragma unroll
        for (int a = 0; a < 4; a++) {
            const int am = R * 4 + a;
            const int lpr = ((a >> 1) & 1) * 8 + wc * 2;
            const int cs = ((a & 1) << 1) + (h4 >> 1);
#pragma unroll
            for (int bn = 0; bn < 4; bn++) {
                const int lp = lpr + (bn >> 1);
                const int e = ((bn & 1) << 4) + rl;
                unsigned int lo = (unsigned int)f2bf(acc[am][bn][0]) |
                                  ((unsigned int)f2bf(acc[am][bn][1]) << 16);
                unsigned int hi = (unsigned int)f2bf(acc[am][bn][2]) |
                                  ((unsigned int)f2bf(acc[am][bn][3]) << 16);
                u32x2 wv; wv[0] = lo; wv[1] = hi;
                *(u32x2*)(sm + wr * 33024 + lp * 2064 + e * 64 +
                          ((cs ^ (e & 3)) << 4) + ((h4 & 1) << 3)) = wv;
            }
        }
        WLGKM0();
        BAR();
        // ---- second GEMM: slot = wid>>2, K quarter = wid&3 ----
        const int slotR = wid >> 2, kq = wid & 3;
        f32x4 ae0 = (f32x4)0.f, ae1 = (f32x4)0.f;
        const char* grow = sm + slotR * 33024 + rl * 2064;
#pragma unroll
        for (int es = 0; es < 8; es++) {
            const int e = kq * 8 + es;
            bf16x8 ga = *(const bf16x8*)(grow + e * 64 + ((h4 ^ (e & 3)) << 4));
            bf16x8 wb0 = *(const bf16x8*)(Wt3 + (size_t)e * 1024 + rl * 32 + h4 * 8);
            bf16x8 wb1 = *(const bf16x8*)(Wt3 + (size_t)e * 1024 + (16 + rl) * 32 + h4 * 8);
            ae0 = __builtin_amdgcn_mfma_f32_16x16x32_bf16(ga, wb0, ae0, 0, 0, 0);
            ae1 = __builtin_amdgcn_mfma_f32_16x16x32_bf16(ga, wb1, ae1, 0, 0, 0);
        }
        WLGKM0();
        BAR();
        // ---- partials: ps[(slot*4+kq)][pair = h4*4+r][ch] (stride 34) ----
#pragma unroll
        for (int r = 0; r < 4; r++) {
            ps[((slotR * 4 + kq) * 16 + h4 * 4 + r) * 34 + rl]      = ae0[r];
            ps[((slotR * 4 + kq) * 16 + h4 * 4 + r) * 34 + 16 + rl] = ae1[r];
        }
        WLGKM0();
        BAR();
        // ---- reduce 4 K-quarters + bias + mask-norm + coalesced store ----
#pragma unroll
        for (int u = 0; u < 2; u++) {
            const int lp = (t >> 5) & 15, ch = t & 31;
            float v = 0.f;
#pragma unroll
            for (int k2 = 0; k2 < 4; k2++)
                v += ps[((u * 4 + k2) * 16 + lp) * 34 + ch];
            const int pi = u * 4 + R * 2 + (lp >> 3), pj = lp & 7;
            const int i = TI * 8 + pi, j = TJ * 8 + pj;
            out[((size_t)(i * N_RES + j)) * CCH + ch] =
                (v + bout[ch]) * inv_norm[(size_t)i * N_RES + j];
        }
        BAR();
    }
}

// ---------------------------------------------------------------------------
extern "C" void kernel_launch(void* const* d_in, const int* in_sizes, int n_in,
                              void* d_out, int out_size, void* d_ws, size_t ws_size,
                              hipStream_t stream)
{
    const float* m    = (const float*)d_in[0];
    const float* mask = (const float*)d_in[1];
    const float* gam  = (const float*)d_in[2];
    const float* bet  = (const float*)d_in[3];
    const float* Wa   = (const float*)d_in[4];
    const float* ba   = (const float*)d_in[5];
    const float* Wb   = (const float*)d_in[6];
    const float* bb   = (const float*)d_in[7];
    const float* Wout = (const float*)d_in[8];
    const float* bout = (const float*)d_in[9];
    float* out = (float*)d_out;

    char* ws = (char*)d_ws;
    char* Ag = ws;                                            //  8,388,608 B
    char* Bg = ws + 8388608;                                  //  8,388,608 B
    unsigned short* Wt3 = (unsigned short*)(ws + 16777216);   //     65,536 B
    float* inv_norm = (float*)(ws + 16842752);                //  1,048,576 B

    prep_ab<<<dim3(N_RES), dim3(256), 0, stream>>>(m, mask, gam, bet, Wa, ba, Wb, bb, Ag, Bg);
    kwt<<<dim3(128), dim3(256), 0, stream>>>(Wout, Wt3);
    knorm<<<dim3(64), dim3(256), 0, stream>>>(mask, inv_norm);
    kmain5<<<dim3(4096), dim3(512), 0, stream>>>(Ag, Bg, Wt3, inv_norm, bout, out);
}